// Round 6
// baseline (1220.341 us; speedup 1.0000x reference)
//
#include <hip/hip_runtime.h>
#include <stdint.h>

#define FAN_IN  512
#define FAN_MID 256
#define FAN_OUT 64
#define NEG_SLOPE 0.01f

typedef __bf16 bf16_t;
typedef bf16_t bf16x8 __attribute__((ext_vector_type(8)));
typedef float  f32x4  __attribute__((ext_vector_type(4)));
typedef unsigned short u16x8 __attribute__((ext_vector_type(8)));

__device__ inline unsigned short f2b(float f) {
    union { float f; unsigned int u; } v; v.f = f;
    unsigned int u = v.u;
    return (unsigned short)((u + 0x7fffu + ((u >> 16) & 1u)) >> 16); // RNE
}
__device__ inline float b2f(unsigned short u) {
    union { unsigned int u; float f; } v; v.u = ((unsigned int)u) << 16; return v.f;
}

// ---------------- direct per-node CSR build (atomic) ----------------
__global__ void zero_kernel(int* p, int n) {
    int i = blockIdx.x * 256 + threadIdx.x;
    if (i < n) p[i] = 0;
}

// per-node histogram via global atomics (3.2M adds over 100k counters)
__global__ __launch_bounds__(256) void hist_n(const int* __restrict__ dst,
                                              int* __restrict__ cnt, int E) {
    int i = blockIdx.x * 256 + threadIdx.x;
    if (i < E) atomicAdd(&cnt[dst[i]], 1);
}

// single-block scan over node counts -> offsets[] and cursor copy cur[]
__global__ void scan_n(const int* __restrict__ cnt, int* __restrict__ offsets,
                       int* __restrict__ cur, int Nn, int E) {
    __shared__ int part[1024];
    int t = threadIdx.x;
    int chunk = (Nn + 1023) >> 10;
    int s = t * chunk;
    int e = s + chunk; if (e > Nn) e = Nn;
    int sum = 0;
    for (int i = s; i < e; i++) sum += cnt[i];
    part[t] = sum;
    __syncthreads();
    for (int off = 1; off < 1024; off <<= 1) {
        int v = (t >= off) ? part[t - off] : 0;
        __syncthreads();
        part[t] += v;
        __syncthreads();
    }
    int run = (t == 0) ? 0 : part[t - 1];
    for (int i = s; i < e; i++) {
        offsets[i] = run;
        cur[i] = run;
        run += cnt[i];
    }
    if (t == 1023) offsets[Nn] = E;
}

// direct scatter into two 8-byte CSR streams: csr1=(src,w1), csr2=(src,w2).
// Order within a node is nondeterministic (atomic cursor) — affects only
// f32 summation order downstream, within tolerance.
__global__ __launch_bounds__(256) void scatter_n(const int* __restrict__ src,
                                                 const int* __restrict__ dst,
                                                 const float* __restrict__ w1,
                                                 const float* __restrict__ w2,
                                                 int* __restrict__ cur,
                                                 uint2* __restrict__ csr1,
                                                 uint2* __restrict__ csr2, int E) {
    int i = blockIdx.x * 256 + threadIdx.x;
    if (i >= E) return;
    int d = dst[i];
    int pos = atomicAdd(&cur[d], 1);
    uint2 r1; r1.x = (unsigned int)src[i]; r1.y = __float_as_uint(w1[i]);
    uint2 r2; r2.x = (unsigned int)src[i]; r2.y = __float_as_uint(w2[i]);
    csr1[pos] = r1;
    csr2[pos] = r2;
}

// ---------------- weight transpose + bf16 convert: Wt[n][k] = bf16(W[k][n]) ----------------
__global__ void convert_w_kernel(const float* __restrict__ W, unsigned short* __restrict__ Wt,
                                 int K, int N) {
    int idx = blockIdx.x * 256 + threadIdx.x;
    if (idx >= K * N) return;
    int k = idx / N, n = idx % N;
    Wt[(size_t)n * K + k] = f2b(W[idx]);
}

// ---------------- bf16 MFMA GEMM: C[M,N] = A[M,K] * Bt[N,K]^T, C in bf16 ----------------
template<int K, int N, bool A_F32>
__global__ __launch_bounds__(256) void gemm_bt(const void* __restrict__ Ap,
                                               const unsigned short* __restrict__ Bt,
                                               unsigned short* __restrict__ C, int M) {
    constexpr int LDT = 40;
    constexpr int NW  = N / 64;
    __shared__ unsigned short As[64 * LDT];
    __shared__ unsigned short Bs[N * LDT];
    const int m0   = blockIdx.x * 64;
    const int tid  = threadIdx.x;
    const int lane = tid & 63;
    const int w    = tid >> 6;
    const int lrow = tid >> 2;
    const int lseg = (tid & 3) * 8;
    const int q    = lane >> 4;
    const int mm   = lane & 15;

    f32x4 acc[4][NW] = {};

    for (int k0 = 0; k0 < K; k0 += 32) {
        __syncthreads();
        {
            int gm = m0 + lrow;
            u16x8 av;
            if (A_F32) {
                const float* A32 = (const float*)Ap;
                if (gm < M) {
                    const float4* pp = (const float4*)(A32 + (size_t)gm * K + k0 + lseg);
                    float4 f0 = pp[0], f1 = pp[1];
                    av[0] = f2b(f0.x); av[1] = f2b(f0.y); av[2] = f2b(f0.z); av[3] = f2b(f0.w);
                    av[4] = f2b(f1.x); av[5] = f2b(f1.y); av[6] = f2b(f1.z); av[7] = f2b(f1.w);
                } else av = (u16x8)0;
            } else {
                const unsigned short* A16 = (const unsigned short*)Ap;
                if (gm < M) av = *(const u16x8*)(A16 + (size_t)gm * K + k0 + lseg);
                else        av = (u16x8)0;
            }
            *(u16x8*)&As[lrow * LDT + lseg] = av;
        }
#pragma unroll
        for (int r = 0; r < N / 64; r++) {
            int nr = r * 64 + lrow;
            *(u16x8*)&Bs[nr * LDT + lseg] =
                *(const u16x8*)(Bt + (size_t)nr * K + k0 + lseg);
        }
        __syncthreads();

        bf16x8 a[4], b[NW];
#pragma unroll
        for (int mi = 0; mi < 4; mi++)
            a[mi] = *(const bf16x8*)&As[(mi * 16 + mm) * LDT + q * 8];
#pragma unroll
        for (int ni = 0; ni < NW; ni++)
            b[ni] = *(const bf16x8*)&Bs[(w * NW * 16 + ni * 16 + mm) * LDT + q * 8];
#pragma unroll
        for (int mi = 0; mi < 4; mi++)
#pragma unroll
            for (int ni = 0; ni < NW; ni++)
                acc[mi][ni] = __builtin_amdgcn_mfma_f32_16x16x32_bf16(a[mi], b[ni], acc[mi][ni], 0, 0, 0);
    }

#pragma unroll
    for (int mi = 0; mi < 4; mi++)
#pragma unroll
        for (int ni = 0; ni < NW; ni++)
#pragma unroll
            for (int r = 0; r < 4; r++) {
                int row = m0 + mi * 16 + q * 4 + r;
                if (row < M)
                    C[(size_t)row * N + w * NW * 16 + ni * 16 + mm] = f2b(acc[mi][ni][r]);
            }
}

// ---------------- aggregation layer 1 FUSED with layer-2 GEMM ----------------
// Gather structure identical to R5 (lanes 0-31 even edge, 32-63 odd edge,
// 16 B/lane row slices). Each wave handles 4 nodes sequentially; the resulting
// 4x256 bf16 h-rows go to LDS and one 16x16x32-MFMA matvec (M=16, rows 4-15
// garbage/unused) computes support2 = bf16(h @ W2) directly. h never touches
// global memory; gemm2 kernel is eliminated.
__global__ __launch_bounds__(256) void agg1_fused(const unsigned short* __restrict__ S,
                                                  const int* __restrict__ offsets,
                                                  const uint2* __restrict__ edges,
                                                  const float* __restrict__ b1,
                                                  const unsigned short* __restrict__ W2t,
                                                  unsigned short* __restrict__ S2, int Nn) {
    __shared__ unsigned short Hs[4][16][264];   // per-wave 16x256 tile, 528B row stride
    int wv   = threadIdx.x >> 6;
    int lane = threadIdx.x & 63;
    const int half = lane >> 5;   // 0: even edge, 1: odd edge
    const int elo  = lane & 31;   // feature block elo*8 .. elo*8+7
    const int q    = lane >> 4;   // MFMA k-group
    const int mm   = lane & 15;   // MFMA row/col
    int nodeBase = blockIdx.x * 16 + wv * 4;

    for (int nl = 0; nl < 4; nl++) {
        int node = nodeBase + nl;
        if (node >= Nn) break;    // uniform across wave
        int s = offsets[node], e = offsets[node + 1];
        float acc[8] = {0.f, 0.f, 0.f, 0.f, 0.f, 0.f, 0.f, 0.f};
        int i = s;
        for (; i + 16 <= e; i += 16) {
            uint2 ed[8];
#pragma unroll
            for (int p = 0; p < 8; p++) ed[p] = edges[i + 2 * p + half];
            u16x8 v[8];
#pragma unroll
            for (int p = 0; p < 8; p++)
                v[p] = *(const u16x8*)(S + (size_t)ed[p].x * 256 + elo * 8);
#pragma unroll
            for (int p = 0; p < 8; p++) {
                float w = __uint_as_float(ed[p].y);
#pragma unroll
                for (int k = 0; k < 8; k++) acc[k] += w * b2f(v[p][k]);
            }
        }
        for (; i + 2 <= e; i += 2) {
            uint2 ev = edges[i + half];
            float w = __uint_as_float(ev.y);
            u16x8 v = *(const u16x8*)(S + (size_t)ev.x * 256 + elo * 8);
#pragma unroll
            for (int k = 0; k < 8; k++) acc[k] += w * b2f(v[k]);
        }
        if (i < e) {
            uint2 ev = edges[i];
            float w = half ? 0.f : __uint_as_float(ev.y);
            u16x8 v = *(const u16x8*)(S + (size_t)ev.x * 256 + elo * 8);
#pragma unroll
            for (int k = 0; k < 8; k++) acc[k] += w * b2f(v[k]);
        }
#pragma unroll
        for (int k = 0; k < 8; k++) acc[k] += __shfl_xor(acc[k], 32);
        if (half == 0) {
            float4 bb0 = ((const float4*)b1)[elo * 2];
            float4 bb1 = ((const float4*)b1)[elo * 2 + 1];
            float r[8];
            r[0] = acc[0] + bb0.x; r[1] = acc[1] + bb0.y;
            r[2] = acc[2] + bb0.z; r[3] = acc[3] + bb0.w;
            r[4] = acc[4] + bb1.x; r[5] = acc[5] + bb1.y;
            r[6] = acc[6] + bb1.z; r[7] = acc[7] + bb1.w;
            u16x8 o;
#pragma unroll
            for (int k = 0; k < 8; k++) {
                float t = r[k] > 0.f ? r[k] : r[k] * NEG_SLOPE;
                o[k] = f2b(t);
            }
            *(u16x8*)&Hs[wv][nl][elo * 8] = o;
        }
    }
    // make this wave's LDS writes visible before fragment reads (in-wave, no barrier)
    asm volatile("s_waitcnt lgkmcnt(0)" ::: "memory");

    // matvec: C[16x64] = Hs[wv][16x256] @ W2[256x64], only rows 0-3 real.
    // Fragment layout identical to gemm_bt (harness-verified):
    //   A: lane(q,mm) holds A[row=mm][k=ks*32+q*8 .. +7]
    //   B: lane(q,mm) holds B[col=ni*16+mm][k=ks*32+q*8 .. +7]  (W2t is n-major)
    //   C: col=lane&15, row=(lane>>4)*4+reg
    f32x4 acc2[4] = {};
#pragma unroll
    for (int ks = 0; ks < 8; ks++) {
        bf16x8 a = *(const bf16x8*)&Hs[wv][mm][ks * 32 + q * 8];
#pragma unroll
        for (int ni = 0; ni < 4; ni++) {
            bf16x8 b = *(const bf16x8*)(W2t + (size_t)(ni * 16 + mm) * 256 + ks * 32 + q * 8);
            acc2[ni] = __builtin_amdgcn_mfma_f32_16x16x32_bf16(a, b, acc2[ni], 0, 0, 0);
        }
    }
    if (q == 0) {
#pragma unroll
        for (int r = 0; r < 4; r++) {
            int node = nodeBase + r;
            if (node < Nn) {
#pragma unroll
                for (int ni = 0; ni < 4; ni++)
                    S2[(size_t)node * 64 + ni * 16 + mm] = f2b(acc2[ni][r]);
            }
        }
    }
}

// ---------------- aggregation layer 2 + bias + log_softmax ----------------
// Lane mapping: slot = lane>>3 picks one of 8 edges, fblk = lane&7 picks 8 of 64 features.
__global__ __launch_bounds__(256) void agg2_kernel(const unsigned short* __restrict__ S,
                                                   const int* __restrict__ offsets,
                                                   const uint2* __restrict__ edges,
                                                   const float* __restrict__ b2,
                                                   float* __restrict__ out, int Nn) {
    int wave = threadIdx.x >> 6;
    int lane = threadIdx.x & 63;
    int node = blockIdx.x * 4 + wave;
    if (node >= Nn) return;
    int s = offsets[node], e = offsets[node + 1];
    const int slot = lane >> 3;
    const int fblk = lane & 7;
    float acc[8] = {0.f, 0.f, 0.f, 0.f, 0.f, 0.f, 0.f, 0.f};
    int i = s;
    for (; i + 16 <= e; i += 16) {
        uint2 e0 = edges[i + slot];
        uint2 e1 = edges[i + 8 + slot];
        u16x8 v0 = *(const u16x8*)(S + (size_t)e0.x * 64 + fblk * 8);
        u16x8 v1 = *(const u16x8*)(S + (size_t)e1.x * 64 + fblk * 8);
        float w0 = __uint_as_float(e0.y), w1 = __uint_as_float(e1.y);
#pragma unroll
        for (int k = 0; k < 8; k++) acc[k] += w0 * b2f(v0[k]) + w1 * b2f(v1[k]);
    }
    for (; i + 8 <= e; i += 8) {
        uint2 ev = edges[i + slot];
        u16x8 v = *(const u16x8*)(S + (size_t)ev.x * 64 + fblk * 8);
        float w = __uint_as_float(ev.y);
#pragma unroll
        for (int k = 0; k < 8; k++) acc[k] += w * b2f(v[k]);
    }
    int rem = e - i;
    if (rem > 0) {
        int j = i + (slot < rem ? slot : rem - 1);
        uint2 ev = edges[j];
        float w = (slot < rem) ? __uint_as_float(ev.y) : 0.f;
        u16x8 v = *(const u16x8*)(S + (size_t)ev.x * 64 + fblk * 8);
#pragma unroll
        for (int k = 0; k < 8; k++) acc[k] += w * b2f(v[k]);
    }
#pragma unroll
    for (int k = 0; k < 8; k++) {
        acc[k] += __shfl_xor(acc[k], 8);
        acc[k] += __shfl_xor(acc[k], 16);
        acc[k] += __shfl_xor(acc[k], 32);
    }
    float4 bb0 = ((const float4*)b2)[fblk * 2];
    float4 bb1 = ((const float4*)b2)[fblk * 2 + 1];
    float logit[8];
    logit[0] = acc[0] + bb0.x; logit[1] = acc[1] + bb0.y;
    logit[2] = acc[2] + bb0.z; logit[3] = acc[3] + bb0.w;
    logit[4] = acc[4] + bb1.x; logit[5] = acc[5] + bb1.y;
    logit[6] = acc[6] + bb1.z; logit[7] = acc[7] + bb1.w;
    float m = logit[0];
#pragma unroll
    for (int k = 1; k < 8; k++) m = fmaxf(m, logit[k]);
    m = fmaxf(m, __shfl_xor(m, 1));
    m = fmaxf(m, __shfl_xor(m, 2));
    m = fmaxf(m, __shfl_xor(m, 4));
    float sum = 0.f;
#pragma unroll
    for (int k = 0; k < 8; k++) sum += expf(logit[k] - m);
    sum += __shfl_xor(sum, 1);
    sum += __shfl_xor(sum, 2);
    sum += __shfl_xor(sum, 4);
    float ls = logf(sum);
    if (slot == 0) {
        float* op = out + (size_t)node * 64 + fblk * 8;
        float4 o0, o1;
        o0.x = logit[0] - m - ls; o0.y = logit[1] - m - ls;
        o0.z = logit[2] - m - ls; o0.w = logit[3] - m - ls;
        o1.x = logit[4] - m - ls; o1.y = logit[5] - m - ls;
        o1.z = logit[6] - m - ls; o1.w = logit[7] - m - ls;
        ((float4*)op)[0] = o0;
        ((float4*)op)[1] = o1;
    }
}

// ---------------- launch ----------------
extern "C" void kernel_launch(void* const* d_in, const int* in_sizes, int n_in,
                              void* d_out, int out_size, void* d_ws, size_t ws_size,
                              hipStream_t stream) {
    const float* x    = (const float*)d_in[0];
    const int*   esrc = (const int*)d_in[1];
    const int*   edst = (const int*)d_in[2];
    const float* ew1  = (const float*)d_in[3];
    const float* ew2  = (const float*)d_in[4];
    const float* W1   = (const float*)d_in[5];
    const float* b1   = (const float*)d_in[6];
    const float* W2   = (const float*)d_in[7];
    const float* b2   = (const float*)d_in[8];
    float* out = (float*)d_out;
    const int Nn = in_sizes[0] / FAN_IN;   // 100000
    const int E  = in_sizes[1];            // 3200000

    char* p = (char*)d_ws;
    auto alloc = [&](size_t bytes) -> char* {
        char* r = p;
        p += (bytes + 255) & ~(size_t)255;
        return r;
    };
    unsigned short* support1 = (unsigned short*)alloc((size_t)Nn * FAN_MID * 2);  // 51.2 MB
    unsigned short* support2 = (unsigned short*)alloc((size_t)Nn * FAN_OUT * 2);  // 12.8 MB
    unsigned short* W1t      = (unsigned short*)alloc((size_t)FAN_IN * FAN_MID * 2);
    unsigned short* W2t      = (unsigned short*)alloc((size_t)FAN_MID * FAN_OUT * 2);
    int*            cnt      = (int*)alloc((size_t)Nn * 4);
    int*            cur      = (int*)alloc((size_t)Nn * 4);
    int*            offsets  = (int*)alloc(((size_t)Nn + 1) * 4);
    uint2*          csr1     = (uint2*)alloc((size_t)E * 8);                       // 25.6 MB
    uint2*          csr2     = (uint2*)alloc((size_t)E * 8);                       // 25.6 MB
    // total ~117 MB

    const int EB = (E + 255) / 256;

    // direct CSR build (atomic; within-node order nondeterministic)
    zero_kernel<<<(Nn + 255) / 256, 256, 0, stream>>>(cnt, Nn);
    hist_n<<<EB, 256, 0, stream>>>(edst, cnt, E);
    scan_n<<<1, 1024, 0, stream>>>(cnt, offsets, cur, Nn, E);
    scatter_n<<<EB, 256, 0, stream>>>(esrc, edst, ew1, ew2, cur, csr1, csr2, E);

    // weights: transpose + bf16
    convert_w_kernel<<<(FAN_IN * FAN_MID + 255) / 256, 256, 0, stream>>>(W1, W1t, FAN_IN, FAN_MID);
    convert_w_kernel<<<(FAN_MID * FAN_OUT + 255) / 256, 256, 0, stream>>>(W2, W2t, FAN_MID, FAN_OUT);

    // layer 1: support1 = bf16(x @ W1)
    gemm_bt<FAN_IN, FAN_MID, true><<<dim3((Nn + 63) / 64, 1), 256, 0, stream>>>(
        x, W1t, support1, Nn);

    // fused: agg1 + leaky_relu + (h @ W2) -> support2  (gemm2 + h buffer eliminated)
    agg1_fused<<<(Nn + 15) / 16, 256, 0, stream>>>(support1, offsets, csr1, b1, W2t, support2, Nn);

    // layer 2 aggregation + bias + log_softmax
    agg2_kernel<<<(Nn + 3) / 4, 256, 0, stream>>>(support2, offsets, csr2, b2, out, Nn);
}

// Round 8
// 825.301 us; speedup vs baseline: 1.4787x; 1.4787x over previous
//
#include <hip/hip_runtime.h>
#include <stdint.h>

#define FAN_IN  512
#define FAN_MID 256
#define FAN_OUT 64
#define NEG_SLOPE 0.01f
#define NPB 128         // nodes per bucket (bucket = dst >> 7)
#define MAXNB 1024      // LDS bound for bucket arrays (supports Nn <= 131072)
#define BPART 256       // partition blocks (= part_scan blockDim)

typedef __bf16 bf16_t;
typedef bf16_t bf16x8 __attribute__((ext_vector_type(8)));
typedef float  f32x4  __attribute__((ext_vector_type(4)));
typedef unsigned short u16x8 __attribute__((ext_vector_type(8)));

__device__ inline unsigned short f2b(float f) {
    union { float f; unsigned int u; } v; v.f = f;
    unsigned int u = v.u;
    return (unsigned short)((u + 0x7fffu + ((u >> 16) & 1u)) >> 16); // RNE
}
__device__ inline float b2f(unsigned short u) {
    union { unsigned int u; float f; } v; v.u = ((unsigned int)u) << 16; return v.f;
}

// ---------------- deterministic bucketed partition ----------------
__global__ void zerob_kernel(int* p, int n) {
    int i = blockIdx.x * 256 + threadIdx.x;
    if (i < n) p[i] = 0;
}

// per-block LDS histogram -> gcount[blk][bucket] (block-major) + bucket totals
__global__ __launch_bounds__(256) void part_hist(const int* __restrict__ dst,
                                                 int* __restrict__ gcount,
                                                 int* __restrict__ bcount,
                                                 int E, int nb, int chunk) {
    __shared__ int lc[MAXNB];
    int blk = blockIdx.x;
    for (int i = threadIdx.x; i < nb; i += 256) lc[i] = 0;
    __syncthreads();
    int s = blk * chunk;
    int e = s + chunk; if (e > E) e = E;
    for (int i = s + threadIdx.x; i < e; i += 256)
        atomicAdd(&lc[dst[i] >> 7], 1);
    __syncthreads();
    for (int i = threadIdx.x; i < nb; i += 256) {
        int c = lc[i];
        gcount[blk * nb + i] = c;
        if (c) atomicAdd(&bcount[i], c);
    }
}

// single-block scan over bucket totals -> boff
__global__ void bscan_kernel(const int* __restrict__ bcount, int* __restrict__ boff,
                             int nb, int E) {
    __shared__ int part[1024];
    int t = threadIdx.x;
    int chunk = (nb + 1023) >> 10;
    int s = t * chunk;
    int e = s + chunk; if (e > nb) e = nb;
    int sum = 0;
    for (int i = s; i < e; i++) sum += bcount[i];
    part[t] = sum;
    __syncthreads();
    for (int off = 1; off < 1024; off <<= 1) {
        int v = (t >= off) ? part[t - off] : 0;
        __syncthreads();
        part[t] += v;
        __syncthreads();
    }
    int run = (t == 0) ? 0 : part[t - 1];
    for (int i = s; i < e; i++) {
        boff[i] = run;
        run += bcount[i];
    }
    if (t == 1023) boff[nb] = E;
}

// one block per bucket: exclusive scan of the BPART per-block counts -> gbase[blk][bucket]
__global__ __launch_bounds__(BPART) void part_scan(const int* __restrict__ gcount,
                                                   const int* __restrict__ boff,
                                                   int* __restrict__ gbase, int nb) {
    __shared__ int v[BPART];
    int bucket = blockIdx.x;
    int t = threadIdx.x;
    int val = gcount[t * nb + bucket];
    v[t] = val;
    __syncthreads();
    for (int off = 1; off < BPART; off <<= 1) {
        int x = (t >= off) ? v[t - off] : 0;
        __syncthreads();
        v[t] += x;
        __syncthreads();
    }
    gbase[t * nb + bucket] = (t == 0 ? 0 : v[t - 1]) + boff[bucket];
}

// each block re-reads its chunk; positions from LDS cursors seeded with gbase.
__global__ __launch_bounds__(256) void part_scatter(const int* __restrict__ src,
                                                    const int* __restrict__ dst,
                                                    const float* __restrict__ w1,
                                                    const float* __restrict__ w2,
                                                    const int* __restrict__ gbase,
                                                    uint4* __restrict__ bstage,
                                                    int E, int nb, int chunk) {
    __shared__ int lcur[MAXNB];
    int blk = blockIdx.x;
    for (int i = threadIdx.x; i < nb; i += 256) lcur[i] = gbase[blk * nb + i];
    __syncthreads();
    int s = blk * chunk;
    int e = s + chunk; if (e > E) e = E;
    for (int i = s + threadIdx.x; i < e; i += 256) {
        int d = dst[i];
        int pos = atomicAdd(&lcur[d >> 7], 1);
        uint4 v;
        v.x = (unsigned int)src[i];
        v.y = __float_as_uint(w1[i]);
        v.z = __float_as_uint(w2[i]);
        v.w = (unsigned int)d;
        bstage[pos] = v;
    }
}

// one block per bucket: LDS count+scan (emits offsets[] for free), local re-scatter.
// Emits TWO 8-byte CSR streams: csr1=(src,w1) for agg1, csr2=(src,w2) for agg2.
__global__ __launch_bounds__(256) void bsort_kernel(const uint4* __restrict__ bstage,
                                                    const int* __restrict__ boff,
                                                    int* __restrict__ offsets,
                                                    uint2* __restrict__ csr1,
                                                    uint2* __restrict__ csr2,
                                                    int Nn, int E, int nb) {
    __shared__ int cnt[NPB];
    __shared__ int scn[NPB];
    __shared__ int cur[NPB];
    int b = blockIdx.x;
    int t = threadIdx.x;
    int base = boff[b], end = boff[b + 1];
    int n0 = b * NPB;
    if (t < NPB) cnt[t] = 0;
    __syncthreads();
    for (int i = base + t; i < end; i += 256)
        atomicAdd(&cnt[bstage[i].w - n0], 1);
    __syncthreads();
    if (t == 0) {
        int run = 0;
        for (int j = 0; j < NPB; j++) { scn[j] = run; run += cnt[j]; }
    }
    __syncthreads();
    if (t < NPB) {
        cur[t] = scn[t];
        int n = n0 + t;
        if (n < Nn) offsets[n] = base + scn[t];
    }
    if (b == nb - 1 && t == 0) offsets[Nn] = E;
    __syncthreads();
    for (int i = base + t; i < end; i += 256) {
        uint4 rec = bstage[i];
        int lp = atomicAdd(&cur[rec.w - n0], 1);
        uint2 r1; r1.x = rec.x; r1.y = rec.y;
        uint2 r2; r2.x = rec.x; r2.y = rec.z;
        csr1[base + lp] = r1;
        csr2[base + lp] = r2;
    }
}

// ---------------- weight transpose + bf16 convert: Wt[n][k] = bf16(W[k][n]) ----------------
__global__ void convert_w_kernel(const float* __restrict__ W, unsigned short* __restrict__ Wt,
                                 int K, int N) {
    int idx = blockIdx.x * 256 + threadIdx.x;
    if (idx >= K * N) return;
    int k = idx / N, n = idx % N;
    Wt[(size_t)n * K + k] = f2b(W[idx]);
}

// ---------------- bf16 MFMA GEMM: C[M,N] = A[M,K] * Bt[N,K]^T, C in bf16 ----------------
template<int K, int N, bool A_F32>
__global__ __launch_bounds__(256) void gemm_bt(const void* __restrict__ Ap,
                                               const unsigned short* __restrict__ Bt,
                                               unsigned short* __restrict__ C, int M) {
    constexpr int LDT = 40;
    constexpr int NW  = N / 64;
    __shared__ unsigned short As[64 * LDT];
    __shared__ unsigned short Bs[N * LDT];
    const int m0   = blockIdx.x * 64;
    const int tid  = threadIdx.x;
    const int lane = tid & 63;
    const int w    = tid >> 6;
    const int lrow = tid >> 2;
    const int lseg = (tid & 3) * 8;
    const int q    = lane >> 4;
    const int mm   = lane & 15;

    f32x4 acc[4][NW] = {};

    for (int k0 = 0; k0 < K; k0 += 32) {
        __syncthreads();
        {
            int gm = m0 + lrow;
            u16x8 av;
            if (A_F32) {
                const float* A32 = (const float*)Ap;
                if (gm < M) {
                    const float4* pp = (const float4*)(A32 + (size_t)gm * K + k0 + lseg);
                    float4 f0 = pp[0], f1 = pp[1];
                    av[0] = f2b(f0.x); av[1] = f2b(f0.y); av[2] = f2b(f0.z); av[3] = f2b(f0.w);
                    av[4] = f2b(f1.x); av[5] = f2b(f1.y); av[6] = f2b(f1.z); av[7] = f2b(f1.w);
                } else av = (u16x8)0;
            } else {
                const unsigned short* A16 = (const unsigned short*)Ap;
                if (gm < M) av = *(const u16x8*)(A16 + (size_t)gm * K + k0 + lseg);
                else        av = (u16x8)0;
            }
            *(u16x8*)&As[lrow * LDT + lseg] = av;
        }
#pragma unroll
        for (int r = 0; r < N / 64; r++) {
            int nr = r * 64 + lrow;
            *(u16x8*)&Bs[nr * LDT + lseg] =
                *(const u16x8*)(Bt + (size_t)nr * K + k0 + lseg);
        }
        __syncthreads();

        bf16x8 a[4], b[NW];
#pragma unroll
        for (int mi = 0; mi < 4; mi++)
            a[mi] = *(const bf16x8*)&As[(mi * 16 + mm) * LDT + q * 8];
#pragma unroll
        for (int ni = 0; ni < NW; ni++)
            b[ni] = *(const bf16x8*)&Bs[(w * NW * 16 + ni * 16 + mm) * LDT + q * 8];
#pragma unroll
        for (int mi = 0; mi < 4; mi++)
#pragma unroll
            for (int ni = 0; ni < NW; ni++)
                acc[mi][ni] = __builtin_amdgcn_mfma_f32_16x16x32_bf16(a[mi], b[ni], acc[mi][ni], 0, 0, 0);
    }

#pragma unroll
    for (int mi = 0; mi < 4; mi++)
#pragma unroll
        for (int ni = 0; ni < NW; ni++)
#pragma unroll
            for (int r = 0; r < 4; r++) {
                int row = m0 + mi * 16 + q * 4 + r;
                if (row < M)
                    C[(size_t)row * N + w * NW * 16 + ni * 16 + mm] = f2b(acc[mi][ni][r]);
            }
}

// ---------------- aggregation layer 1 FUSED with layer-2 GEMM (block-level tile) ----------------
// Gather identical to R5. 4 waves x 4 nodes = 16 h-rows in one 8.4 KB block-shared
// LDS tile; after one barrier each wave computes one 16x16 quadrant of
// support2 = bf16(h @ W2) with 8 MFMAs. h never touches global; gemm2 eliminated.
__global__ __launch_bounds__(256) void agg1_fused(const unsigned short* __restrict__ S,
                                                  const int* __restrict__ offsets,
                                                  const uint2* __restrict__ edges,
                                                  const float* __restrict__ b1,
                                                  const unsigned short* __restrict__ W2t,
                                                  unsigned short* __restrict__ S2, int Nn) {
    __shared__ unsigned short Hs[16][264];   // 16 x 256 bf16, 528B row stride (8448 B)
    int wv   = threadIdx.x >> 6;
    int lane = threadIdx.x & 63;
    const int half = lane >> 5;   // 0: even edge, 1: odd edge
    const int elo  = lane & 31;   // feature block elo*8 .. elo*8+7
    const int q    = lane >> 4;   // MFMA k-group
    const int mm   = lane & 15;   // MFMA row/col
    const int node0 = blockIdx.x * 16;

    for (int nl = 0; nl < 4; nl++) {
        int node = node0 + wv * 4 + nl;
        int s = 0, e = 0;
        if (node < Nn) { s = offsets[node]; e = offsets[node + 1]; }
        float acc[8] = {0.f, 0.f, 0.f, 0.f, 0.f, 0.f, 0.f, 0.f};
        int i = s;
        for (; i + 16 <= e; i += 16) {
            uint2 ed[8];
#pragma unroll
            for (int p = 0; p < 8; p++) ed[p] = edges[i + 2 * p + half];
            u16x8 v[8];
#pragma unroll
            for (int p = 0; p < 8; p++)
                v[p] = *(const u16x8*)(S + (size_t)ed[p].x * 256 + elo * 8);
#pragma unroll
            for (int p = 0; p < 8; p++) {
                float w = __uint_as_float(ed[p].y);
#pragma unroll
                for (int k = 0; k < 8; k++) acc[k] += w * b2f(v[p][k]);
            }
        }
        for (; i + 2 <= e; i += 2) {
            uint2 ev = edges[i + half];
            float w = __uint_as_float(ev.y);
            u16x8 v = *(const u16x8*)(S + (size_t)ev.x * 256 + elo * 8);
#pragma unroll
            for (int k = 0; k < 8; k++) acc[k] += w * b2f(v[k]);
        }
        if (i < e) {
            uint2 ev = edges[i];
            float w = half ? 0.f : __uint_as_float(ev.y);
            u16x8 v = *(const u16x8*)(S + (size_t)ev.x * 256 + elo * 8);
#pragma unroll
            for (int k = 0; k < 8; k++) acc[k] += w * b2f(v[k]);
        }
#pragma unroll
        for (int k = 0; k < 8; k++) acc[k] += __shfl_xor(acc[k], 32);
        if (half == 0) {
            float4 bb0 = ((const float4*)b1)[elo * 2];
            float4 bb1 = ((const float4*)b1)[elo * 2 + 1];
            float r[8];
            r[0] = acc[0] + bb0.x; r[1] = acc[1] + bb0.y;
            r[2] = acc[2] + bb0.z; r[3] = acc[3] + bb0.w;
            r[4] = acc[4] + bb1.x; r[5] = acc[5] + bb1.y;
            r[6] = acc[6] + bb1.z; r[7] = acc[7] + bb1.w;
            u16x8 o;
#pragma unroll
            for (int k = 0; k < 8; k++) {
                float t = r[k] > 0.f ? r[k] : r[k] * NEG_SLOPE;
                o[k] = f2b(t);
            }
            *(u16x8*)&Hs[wv * 4 + nl][elo * 8] = o;
        }
    }
    __syncthreads();

    // matvec quadrant: C[16 x 16] = Hs[16 x 256] @ W2[256 x cols wv*16..wv*16+15]
    // Fragment layout identical to gemm_bt (harness-verified):
    //   A: lane(q,mm) holds A[row=mm][k=ks*32+q*8 .. +7]
    //   B: lane(q,mm) holds B[col=wv*16+mm][k=ks*32+q*8 .. +7]  (W2t is n-major)
    //   C: col=mm, row=q*4+reg
    f32x4 acc2 = {};
#pragma unroll
    for (int ks = 0; ks < 8; ks++) {
        bf16x8 a = *(const bf16x8*)&Hs[mm][ks * 32 + q * 8];
        bf16x8 b = *(const bf16x8*)(W2t + (size_t)(wv * 16 + mm) * 256 + ks * 32 + q * 8);
        acc2 = __builtin_amdgcn_mfma_f32_16x16x32_bf16(a, b, acc2, 0, 0, 0);
    }
#pragma unroll
    for (int r = 0; r < 4; r++) {
        int node = node0 + q * 4 + r;
        if (node < Nn)
            S2[(size_t)node * 64 + wv * 16 + mm] = f2b(acc2[r]);
    }
}

// ---------------- aggregation layer 2 + bias + log_softmax ----------------
// Lane mapping: slot = lane>>3 picks one of 8 edges, fblk = lane&7 picks 8 of 64 features.
__global__ __launch_bounds__(256) void agg2_kernel(const unsigned short* __restrict__ S,
                                                   const int* __restrict__ offsets,
                                                   const uint2* __restrict__ edges,
                                                   const float* __restrict__ b2,
                                                   float* __restrict__ out, int Nn) {
    int wave = threadIdx.x >> 6;
    int lane = threadIdx.x & 63;
    int node = blockIdx.x * 4 + wave;
    if (node >= Nn) return;
    int s = offsets[node], e = offsets[node + 1];
    const int slot = lane >> 3;
    const int fblk = lane & 7;
    float acc[8] = {0.f, 0.f, 0.f, 0.f, 0.f, 0.f, 0.f, 0.f};
    int i = s;
    for (; i + 16 <= e; i += 16) {
        uint2 e0 = edges[i + slot];
        uint2 e1 = edges[i + 8 + slot];
        u16x8 v0 = *(const u16x8*)(S + (size_t)e0.x * 64 + fblk * 8);
        u16x8 v1 = *(const u16x8*)(S + (size_t)e1.x * 64 + fblk * 8);
        float w0 = __uint_as_float(e0.y), w1 = __uint_as_float(e1.y);
#pragma unroll
        for (int k = 0; k < 8; k++) acc[k] += w0 * b2f(v0[k]) + w1 * b2f(v1[k]);
    }
    for (; i + 8 <= e; i += 8) {
        uint2 ev = edges[i + slot];
        u16x8 v = *(const u16x8*)(S + (size_t)ev.x * 64 + fblk * 8);
        float w = __uint_as_float(ev.y);
#pragma unroll
        for (int k = 0; k < 8; k++) acc[k] += w * b2f(v[k]);
    }
    int rem = e - i;
    if (rem > 0) {
        int j = i + (slot < rem ? slot : rem - 1);
        uint2 ev = edges[j];
        float w = (slot < rem) ? __uint_as_float(ev.y) : 0.f;
        u16x8 v = *(const u16x8*)(S + (size_t)ev.x * 64 + fblk * 8);
#pragma unroll
        for (int k = 0; k < 8; k++) acc[k] += w * b2f(v[k]);
    }
#pragma unroll
    for (int k = 0; k < 8; k++) {
        acc[k] += __shfl_xor(acc[k], 8);
        acc[k] += __shfl_xor(acc[k], 16);
        acc[k] += __shfl_xor(acc[k], 32);
    }
    float4 bb0 = ((const float4*)b2)[fblk * 2];
    float4 bb1 = ((const float4*)b2)[fblk * 2 + 1];
    float logit[8];
    logit[0] = acc[0] + bb0.x; logit[1] = acc[1] + bb0.y;
    logit[2] = acc[2] + bb0.z; logit[3] = acc[3] + bb0.w;
    logit[4] = acc[4] + bb1.x; logit[5] = acc[5] + bb1.y;
    logit[6] = acc[6] + bb1.z; logit[7] = acc[7] + bb1.w;
    float m = logit[0];
#pragma unroll
    for (int k = 1; k < 8; k++) m = fmaxf(m, logit[k]);
    m = fmaxf(m, __shfl_xor(m, 1));
    m = fmaxf(m, __shfl_xor(m, 2));
    m = fmaxf(m, __shfl_xor(m, 4));
    float sum = 0.f;
#pragma unroll
    for (int k = 0; k < 8; k++) sum += expf(logit[k] - m);
    sum += __shfl_xor(sum, 1);
    sum += __shfl_xor(sum, 2);
    sum += __shfl_xor(sum, 4);
    float ls = logf(sum);
    if (slot == 0) {
        float* op = out + (size_t)node * 64 + fblk * 8;
        float4 o0, o1;
        o0.x = logit[0] - m - ls; o0.y = logit[1] - m - ls;
        o0.z = logit[2] - m - ls; o0.w = logit[3] - m - ls;
        o1.x = logit[4] - m - ls; o1.y = logit[5] - m - ls;
        o1.z = logit[6] - m - ls; o1.w = logit[7] - m - ls;
        ((float4*)op)[0] = o0;
        ((float4*)op)[1] = o1;
    }
}

// ---------------- launch ----------------
extern "C" void kernel_launch(void* const* d_in, const int* in_sizes, int n_in,
                              void* d_out, int out_size, void* d_ws, size_t ws_size,
                              hipStream_t stream) {
    const float* x    = (const float*)d_in[0];
    const int*   esrc = (const int*)d_in[1];
    const int*   edst = (const int*)d_in[2];
    const float* ew1  = (const float*)d_in[3];
    const float* ew2  = (const float*)d_in[4];
    const float* W1   = (const float*)d_in[5];
    const float* b1   = (const float*)d_in[6];
    const float* W2   = (const float*)d_in[7];
    const float* b2   = (const float*)d_in[8];
    float* out = (float*)d_out;
    const int Nn = in_sizes[0] / FAN_IN;   // 100000
    const int E  = in_sizes[1];            // 3200000
    const int NB = (Nn + NPB - 1) / NPB;   // 782 buckets
    const int chunk = (E + BPART - 1) / BPART;

    char* p = (char*)d_ws;
    auto alloc = [&](size_t bytes) -> char* {
        char* r = p;
        p += (bytes + 255) & ~(size_t)255;
        return r;
    };
    size_t s1_bytes = (size_t)Nn * FAN_MID * 2;       // 51.2 MB
    size_t st_bytes = (size_t)E * 16;                 // 51.2 MB
    // bstage aliases support1: bstage dead before gemm1 writes support1
    char* s1_region = alloc(s1_bytes > st_bytes ? s1_bytes : st_bytes);
    unsigned short* support1 = (unsigned short*)s1_region;
    uint4*          bstage   = (uint4*)s1_region;
    unsigned short* support2 = (unsigned short*)alloc((size_t)Nn * FAN_OUT * 2);  // 12.8 MB
    unsigned short* W1t      = (unsigned short*)alloc((size_t)FAN_IN * FAN_MID * 2);
    unsigned short* W2t      = (unsigned short*)alloc((size_t)FAN_MID * FAN_OUT * 2);
    int*            bcount   = (int*)alloc((size_t)NB * 4);
    int*            boff     = (int*)alloc(((size_t)NB + 1) * 4);
    int*            gcount   = (int*)alloc((size_t)BPART * NB * 4);               // 0.8 MB
    int*            gbase    = (int*)alloc((size_t)BPART * NB * 4);               // 0.8 MB
    int*            offsets  = (int*)alloc(((size_t)Nn + 1) * 4);
    uint2*          csr1     = (uint2*)alloc((size_t)E * 8);                       // 25.6 MB
    uint2*          csr2     = (uint2*)alloc((size_t)E * 8);                       // 25.6 MB
    // total ~118 MB

    // deterministic bucketed CSR build
    zerob_kernel<<<(NB + 255) / 256, 256, 0, stream>>>(bcount, NB);
    part_hist<<<BPART, 256, 0, stream>>>(edst, gcount, bcount, E, NB, chunk);
    bscan_kernel<<<1, 1024, 0, stream>>>(bcount, boff, NB, E);
    part_scan<<<NB, BPART, 0, stream>>>(gcount, boff, gbase, NB);
    part_scatter<<<BPART, 256, 0, stream>>>(esrc, edst, ew1, ew2, gbase, bstage, E, NB, chunk);
    bsort_kernel<<<NB, 256, 0, stream>>>(bstage, boff, offsets, csr1, csr2, Nn, E, NB);

    // weights: transpose + bf16
    convert_w_kernel<<<(FAN_IN * FAN_MID + 255) / 256, 256, 0, stream>>>(W1, W1t, FAN_IN, FAN_MID);
    convert_w_kernel<<<(FAN_MID * FAN_OUT + 255) / 256, 256, 0, stream>>>(W2, W2t, FAN_MID, FAN_OUT);

    // layer 1: support1 = bf16(x @ W1)  (overwrites bstage region — dead now)
    gemm_bt<FAN_IN, FAN_MID, true><<<dim3((Nn + 63) / 64, 1), 256, 0, stream>>>(
        x, W1t, support1, Nn);

    // fused: agg1 + leaky_relu + (h @ W2) -> support2  (gemm2 + h buffer eliminated)
    agg1_fused<<<(Nn + 15) / 16, 256, 0, stream>>>(support1, offsets, csr1, b1, W2t, support2, Nn);

    // layer 2 aggregation + bias + log_softmax
    agg2_kernel<<<(Nn + 3) / 4, 256, 0, stream>>>(support2, offsets, csr2, b2, out, Nn);
}